// Round 2
// 396.625 us; speedup vs baseline: 1.0236x; 1.0236x over previous
//
#include <hip/hip_runtime.h>
#include <hip/hip_bf16.h>

#define H 20
#define Q 32
#define D 64
#define NSTATE 1280
#define CACHE_N 16384
#define NSPLIT 32
#define KCHUNK (CACHE_N / NSPLIT)   // 512 rows per split
#define TK 64                        // rows per tile
#define NTILE (KCHUNK / TK)          // 8 tiles per block

// clang vector type for __builtin_nontemporal_store (HIP float4 is a class,
// not a vector — the builtin rejects it)
typedef float f32x4 __attribute__((ext_vector_type(4)));

// ---------------------------------------------------------------------------
// Tiled GEMM: out[32,1280] (+)= x[32,1280] @ W[1280,1280]^T  (+ bias)
// grid.x = col-block (64 cols each, 20), grid.y = k-split (4), [grid.z = mat]
// NOTE: unroll pragmas are load-bearing — full unroll spilled past 256 VGPRs
// and generated 1 GB of scratch traffic (653 us) in round 1.
// Round 2: register prefetch (1 k-tile lookahead) so the global-load latency
// hides under the 64-iter FMA loop instead of being exposed at each barrier.
// ---------------------------------------------------------------------------
__device__ __forceinline__ void gemm_body(const float* __restrict__ x,
                                          const float* __restrict__ W,
                                          const float* __restrict__ bias,
                                          float* __restrict__ out,
                                          int c0, int ksplit) {
    __shared__ float xs[64][36];   // x^T tile: xs[kk][row]
    __shared__ float ws[64][66];   // W^T tile: ws[kk][col]
    const int t = threadIdx.x;
    const int rt = t >> 5;         // 0..7  -> rows rt*4..rt*4+3
    const int ct = t & 31;         // 0..31 -> cols ct*2..ct*2+1
    float acc[4][2] = {};

    const int kbeg = ksplit * 320;

    // prefetch k-tile 0 into registers
    float4 xv[2], wv[4];
#pragma unroll
    for (int p = 0; p < 2; ++p) {
        int idx = t + p * 256;
        int row = idx >> 4, c4 = idx & 15;
        xv[p] = *(const float4*)(x + row * NSTATE + kbeg + c4 * 4);
    }
#pragma unroll
    for (int p = 0; p < 4; ++p) {
        int idx = t + p * 256;
        int c = idx >> 4, c4 = idx & 15;
        wv[p] = *(const float4*)(W + (long long)(c0 + c) * NSTATE + kbeg + c4 * 4);
    }

#pragma unroll 1
    for (int k0 = kbeg; k0 < kbeg + 320; k0 += 64) {
        __syncthreads();           // previous tile's LDS readers done
        // commit prefetched registers to LDS
#pragma unroll
        for (int p = 0; p < 2; ++p) {
            int idx = t + p * 256;
            int row = idx >> 4, c4 = idx & 15;
            xs[c4 * 4 + 0][row] = xv[p].x; xs[c4 * 4 + 1][row] = xv[p].y;
            xs[c4 * 4 + 2][row] = xv[p].z; xs[c4 * 4 + 3][row] = xv[p].w;
        }
#pragma unroll
        for (int p = 0; p < 4; ++p) {
            int idx = t + p * 256;
            int c = idx >> 4, c4 = idx & 15;
            ws[c4 * 4 + 0][c] = wv[p].x; ws[c4 * 4 + 1][c] = wv[p].y;
            ws[c4 * 4 + 2][c] = wv[p].z; ws[c4 * 4 + 3][c] = wv[p].w;
        }
        __syncthreads();
        // issue next tile's loads now; latency hides under the FMA loop
        if (k0 + 64 < kbeg + 320) {
            const int kn = k0 + 64;
#pragma unroll
            for (int p = 0; p < 2; ++p) {
                int idx = t + p * 256;
                int row = idx >> 4, c4 = idx & 15;
                xv[p] = *(const float4*)(x + row * NSTATE + kn + c4 * 4);
            }
#pragma unroll
            for (int p = 0; p < 4; ++p) {
                int idx = t + p * 256;
                int c = idx >> 4, c4 = idx & 15;
                wv[p] = *(const float4*)(W + (long long)(c0 + c) * NSTATE + kn + c4 * 4);
            }
        }
#pragma unroll 8
        for (int kk = 0; kk < 64; ++kk) {
            float4 xq = *(const float4*)&xs[kk][rt * 4];
            float2 wq = *(const float2*)&ws[kk][ct * 2];
            acc[0][0] += xq.x * wq.x; acc[0][1] += xq.x * wq.y;
            acc[1][0] += xq.y * wq.x; acc[1][1] += xq.y * wq.y;
            acc[2][0] += xq.z * wq.x; acc[2][1] += xq.z * wq.y;
            acc[3][0] += xq.w * wq.x; acc[3][1] += xq.w * wq.y;
        }
    }
#pragma unroll
    for (int r = 0; r < 4; ++r) {
        int i = rt * 4 + r;
#pragma unroll
        for (int cc = 0; cc < 2; ++cc) {
            int c = c0 + ct * 2 + cc;
            float val = acc[r][cc];
            if (ksplit == 0 && bias) val += bias[c];
            atomicAdd(&out[i * NSTATE + c], val);
        }
    }
}

__global__ __launch_bounds__(256, 2)
void gemm_qkv(const float* __restrict__ x,
              const float* __restrict__ Wq, const float* __restrict__ bq,
              const float* __restrict__ Wk,
              const float* __restrict__ Wv, const float* __restrict__ bv,
              float* __restrict__ q, float* __restrict__ k, float* __restrict__ v) {
    const int mat = blockIdx.z;
    const float* W; const float* bias; float* out;
    if (mat == 0)      { W = Wq; bias = bq;      out = q; }
    else if (mat == 1) { W = Wk; bias = nullptr; out = k; }
    else               { W = Wv; bias = bv;      out = v; }
    gemm_body(x, W, bias, out, blockIdx.x * 64, blockIdx.y);
}

__global__ __launch_bounds__(256, 2)
void gemm_one(const float* __restrict__ x, const float* __restrict__ W,
              const float* __restrict__ bias, float* __restrict__ out) {
    gemm_body(x, W, bias, out, blockIdx.x * 64, blockIdx.y);
}

// rowmap[j] = i if positions[i] == j else -1 (rowmap pre-memset to 0xFF)
__global__ void build_rowmap(const int* __restrict__ pos, int* __restrict__ rowmap) {
    int i = threadIdx.x;
    if (i < Q) rowmap[pos[i]] = i;   // duplicate positions: higher i wins (last-set)
}

// ---------------------------------------------------------------------------
// FUSED: cache-update write-through + flash-decoding attention partials.
// grid (NSPLIT, H). Block (sp,h) streams rows [sp*512,(sp+1)*512) x cols
// [h*64,(h+1)*64) of K and V, writes them to the output caches (nontemporal),
// and runs QK^T -> online softmax -> PV on the same data.
//
// Round 2 restructure (latency-bound fix — all pipes were <26% busy):
//  * 1-tile register prefetch: K/V/mask/rowmap loads for tile t+1 are issued
//    right after tile t's LDS commit, hiding ~900cy HBM latency under compute.
//  * Staging loads are UNCONDITIONAL kci/vci reads; replaced rows (rowmap
//    hit, <=32 rows globally) are patched with a rare divergent reload —
//    removes the dependent rowmap->K load chain from the critical path.
//  * Softmax state (m,l,alpha) lives in lane-replicated registers of the
//    owning 32-lane half-wave (query i is touched ONLY by threads with
//    qt==i/4) — removes 3 barriers/tile; only 2 barriers/tile remain.
//  * P stored query-major ps2[i][j]: float2 writes land 2 lanes/bank (free)
//    instead of the old 8-way-conflicted P^T b128 writes; PV reads become
//    2-address b128 broadcasts. ps2 is half-wave-private -> no barrier.
//  * LDS = 51.7 KB -> 3 blocks/CU (was 53.8 KB).
// ---------------------------------------------------------------------------
__global__ __launch_bounds__(256, 3)
void attn_fused(const float* __restrict__ qw,
                const float* __restrict__ kci, const float* __restrict__ vci,
                const float* __restrict__ knew, const float* __restrict__ vnew,
                const int* __restrict__ rowmap, const float* __restrict__ mask,
                float* __restrict__ kc, float* __restrict__ vc,
                float* __restrict__ mpart, float* __restrict__ lpart,
                __hip_bfloat16* __restrict__ opart) {
    const int h  = blockIdx.y;
    const int sp = blockIdx.x;
    const int j_base = sp * KCHUNK;

    __shared__ float qs[D][36];       // q^T (scaled): qs[d][i]
    __shared__ float ks_[D][66];      // K^T tile: ks_[d][j]
    __shared__ float vs[TK][68];      // V tile:   vs[j][d]
    __shared__ float ps2[Q][TK];      // P tile, query-major: ps2[i][j]

    const int t  = threadIdx.x;
    const int qt = t >> 5;            // 0..7 : owns queries qt*4..qt*4+3
    const int kt = t & 31;            // 0..31: 2 keys (QK) / 2 dims (PV)
    const int srow = t >> 4;          // staging row within 16-row group
    const int c4   = t & 15;          // staging 16B-chunk index

    // stage q for this head, fold in scale = 1/sqrt(64) = 0.125
#pragma unroll
    for (int p = 0; p < 2; ++p) {
        int idx = t + p * 256;
        int i = idx >> 4, cc = idx & 15;
        float4 v4 = *(const float4*)(qw + i * NSTATE + h * D + cc * 4);
        const float sc = 0.125f;
        qs[cc * 4 + 0][i] = v4.x * sc; qs[cc * 4 + 1][i] = v4.y * sc;
        qs[cc * 4 + 2][i] = v4.z * sc; qs[cc * 4 + 3][i] = v4.w * sc;
    }

    float m_r[4], l_r[4];
#pragma unroll
    for (int r = 0; r < 4; ++r) { m_r[r] = -1e30f; l_r[r] = 0.f; }
    float oacc[4][2] = {};

    // ---- prefetch tile 0 ----
    float4 ka[4], va[4];
    float2 mk[4];
    int    sr[4];
    {
        const int j0 = j_base;
#pragma unroll
        for (int p = 0; p < 4; ++p) {
            int row = srow + 16 * p;
            long long j = j0 + row;
            sr[p] = rowmap[j];
            ka[p] = *(const float4*)(kci + j * NSTATE + h * D + c4 * 4);
            va[p] = *(const float4*)(vci + j * NSTATE + h * D + c4 * 4);
        }
#pragma unroll
        for (int r = 0; r < 4; ++r)
            mk[r] = *(const float2*)(mask + (long long)(qt * 4 + r) * CACHE_N + j0 + kt * 2);
    }

#pragma unroll 1
    for (int tile = 0; tile < NTILE; ++tile) {
        const int j0 = j_base + tile * TK;
        __syncthreads();   // previous tile's LDS readers done (also drains prefetch)

        // patch replaced rows (rare: only splits containing fresh positions)
#pragma unroll
        for (int p = 0; p < 4; ++p) {
            if (sr[p] >= 0) {
                ka[p] = *(const float4*)(knew + (long long)sr[p] * NSTATE + h * D + c4 * 4);
                va[p] = *(const float4*)(vnew + (long long)sr[p] * NSTATE + h * D + c4 * 4);
            }
        }
        // commit: write-through to output caches (nontemporal — never re-read
        // in-kernel; keeps kci/vci L3-resident) + LDS staging
#pragma unroll
        for (int p = 0; p < 4; ++p) {
            int row = srow + 16 * p;
            long long j = j0 + row;
            __builtin_nontemporal_store(*(const f32x4*)&ka[p], (f32x4*)(kc + j * NSTATE + h * D + c4 * 4));
            __builtin_nontemporal_store(*(const f32x4*)&va[p], (f32x4*)(vc + j * NSTATE + h * D + c4 * 4));
            ks_[c4 * 4 + 0][row] = ka[p].x; ks_[c4 * 4 + 1][row] = ka[p].y;
            ks_[c4 * 4 + 2][row] = ka[p].z; ks_[c4 * 4 + 3][row] = ka[p].w;
            *(float4*)&vs[row][c4 * 4] = va[p];
        }
        __syncthreads();

        // consume mask regs into accumulators BEFORE they get overwritten
        float s[4][2];
#pragma unroll
        for (int r = 0; r < 4; ++r) { s[r][0] = mk[r].x; s[r][1] = mk[r].y; }

        // issue next tile's loads — latency hides under QK/softmax/PV
        if (tile + 1 < NTILE) {
            const int jn = j0 + TK;
#pragma unroll
            for (int p = 0; p < 4; ++p) {
                int row = srow + 16 * p;
                long long j = jn + row;
                sr[p] = rowmap[j];
                ka[p] = *(const float4*)(kci + j * NSTATE + h * D + c4 * 4);
                va[p] = *(const float4*)(vci + j * NSTATE + h * D + c4 * 4);
            }
#pragma unroll
            for (int r = 0; r < 4; ++r)
                mk[r] = *(const float2*)(mask + (long long)(qt * 4 + r) * CACHE_N + jn + kt * 2);
        }

        // QK^T: 4q x 2k per thread (qs read = 2-addr broadcast, ks_ = 2-way free)
#pragma unroll 8
        for (int d = 0; d < D; ++d) {
            float4 qv = *(const float4*)&qs[d][qt * 4];
            float2 kv = *(const float2*)&ks_[d][kt * 2];
            s[0][0] += qv.x * kv.x; s[0][1] += qv.x * kv.y;
            s[1][0] += qv.y * kv.x; s[1][1] += qv.y * kv.y;
            s[2][0] += qv.z * kv.x; s[2][1] += qv.z * kv.y;
            s[3][0] += qv.w * kv.x; s[3][1] += qv.w * kv.y;
        }

        // per-query tile max over the 64 keys (butterfly within half-wave)
        float rmax[4];
#pragma unroll
        for (int r = 0; r < 4; ++r) rmax[r] = fmaxf(s[r][0], s[r][1]);
#pragma unroll
        for (int off = 16; off >= 1; off >>= 1)
#pragma unroll
            for (int r = 0; r < 4; ++r)
                rmax[r] = fmaxf(rmax[r], __shfl_xor(rmax[r], off, 64));

        // online softmax entirely in registers (lane-replicated, no barriers)
        float pr[4][2], rsum[4];
#pragma unroll
        for (int r = 0; r < 4; ++r) {
            float mn = fmaxf(m_r[r], rmax[r]);
            float a  = __expf(m_r[r] - mn);
            m_r[r]   = mn;
            pr[r][0] = __expf(s[r][0] - mn);
            pr[r][1] = __expf(s[r][1] - mn);
            rsum[r]  = pr[r][0] + pr[r][1];
            l_r[r]  *= a;
            oacc[r][0] *= a; oacc[r][1] *= a;
        }
#pragma unroll
        for (int off = 16; off >= 1; off >>= 1)
#pragma unroll
            for (int r = 0; r < 4; ++r)
                rsum[r] += __shfl_xor(rsum[r], off, 64);
#pragma unroll
        for (int r = 0; r < 4; ++r) l_r[r] += rsum[r];

        // write P query-major; half-wave private -> same-wave LDS order, no barrier
#pragma unroll
        for (int r = 0; r < 4; ++r)
            *(float2*)&ps2[qt * 4 + r][kt * 2] = make_float2(pr[r][0], pr[r][1]);

        // PV: 4q x 2d per thread; P reads are b128 broadcasts, V reads 2-way free
#pragma unroll 4
        for (int jb = 0; jb < TK; jb += 4) {
            float4 pA = *(const float4*)&ps2[qt * 4 + 0][jb];
            float4 pB = *(const float4*)&ps2[qt * 4 + 1][jb];
            float4 pC = *(const float4*)&ps2[qt * 4 + 2][jb];
            float4 pD = *(const float4*)&ps2[qt * 4 + 3][jb];
            float pa0[4] = {pA.x, pA.y, pA.z, pA.w};
            float pa1[4] = {pB.x, pB.y, pB.z, pB.w};
            float pa2[4] = {pC.x, pC.y, pC.z, pC.w};
            float pa3[4] = {pD.x, pD.y, pD.z, pD.w};
#pragma unroll
            for (int jj = 0; jj < 4; ++jj) {
                float2 vv = *(const float2*)&vs[jb + jj][kt * 2];
                oacc[0][0] += pa0[jj] * vv.x; oacc[0][1] += pa0[jj] * vv.y;
                oacc[1][0] += pa1[jj] * vv.x; oacc[1][1] += pa1[jj] * vv.y;
                oacc[2][0] += pa2[jj] * vv.x; oacc[2][1] += pa2[jj] * vv.y;
                oacc[3][0] += pa3[jj] * vv.x; oacc[3][1] += pa3[jj] * vv.y;
            }
        }
    }

    const int pb = (h * NSPLIT + sp) * Q;
    if (kt == 0) {
#pragma unroll
        for (int r = 0; r < 4; ++r) {
            mpart[pb + qt * 4 + r] = m_r[r];
            lpart[pb + qt * 4 + r] = l_r[r];
        }
    }
#pragma unroll
    for (int r = 0; r < 4; ++r) {
        int i = qt * 4 + r;
        __hip_bfloat16 hx = __float2bfloat16(oacc[r][0]);
        __hip_bfloat16 hy = __float2bfloat16(oacc[r][1]);
        ushort2 u = make_ushort2(*(unsigned short*)&hx, *(unsigned short*)&hy);
        *(ushort2*)((unsigned short*)opart + (size_t)(pb + i) * D + kt * 2) = u;
    }
}

// Combine split partials -> attention output [32,1280]
__global__ __launch_bounds__(64)
void attn_combine(const float* __restrict__ mpart, const float* __restrict__ lpart,
                  const __hip_bfloat16* __restrict__ opart, float* __restrict__ oattn) {
    const int i = blockIdx.x;   // query
    const int h = blockIdx.y;   // head
    const int d = threadIdx.x;  // dim
    float m[NSPLIT];
    float gm = -1e30f;
#pragma unroll
    for (int s = 0; s < NSPLIT; ++s) {
        m[s] = mpart[(h * NSPLIT + s) * Q + i];
        gm = fmaxf(gm, m[s]);
    }
    float l = 0.f, o = 0.f;
#pragma unroll
    for (int s = 0; s < NSPLIT; ++s) {
        float w = __expf(m[s] - gm);
        l += lpart[(h * NSPLIT + s) * Q + i] * w;
        o += __bfloat162float(opart[(size_t)((h * NSPLIT + s) * Q + i) * D + d]) * w;
    }
    oattn[i * NSTATE + h * D + d] = o / l;
}

// ---------------------------------------------------------------------------
extern "C" void kernel_launch(void* const* d_in, const int* in_sizes, int n_in,
                              void* d_out, int out_size, void* d_ws, size_t ws_size,
                              hipStream_t stream) {
    const float* x    = (const float*)d_in[0];
    const float* kci  = (const float*)d_in[1];
    const float* vci  = (const float*)d_in[2];
    const int*   pos  = (const int*)d_in[3];
    const float* mask = (const float*)d_in[4];
    const float* Wq   = (const float*)d_in[5];
    const float* bq   = (const float*)d_in[6];
    const float* Wk   = (const float*)d_in[7];
    const float* Wv   = (const float*)d_in[8];
    const float* bv   = (const float*)d_in[9];
    const float* Wout = (const float*)d_in[10];
    const float* bout = (const float*)d_in[11];

    float* out  = (float*)d_out;                 // [32*1280]
    float* kc   = out + 40960;                   // [16384*1280]
    float* vc   = kc + CACHE_N * NSTATE;

    // workspace layout (float offsets); total 3,342,336 B — within the
    // footprint proven safe in round 1 (3,358,720 B).
    float* ws      = (float*)d_ws;
    float* kws     = ws;                          // 40960
    float* vws     = ws + 40960;                  // 40960
    float* qws     = ws + 81920;                  // 40960 (reused as oattn)
    float* mpart   = ws + 122880;                 // 20480
    float* lpart   = ws + 143360;                 // 20480
    int*   rowmap  = (int*)(ws + 163840);         // 16384 ints
    __hip_bfloat16* opart = (__hip_bfloat16*)(ws + 180224);  // 1,310,720 bf16
    float* oattn   = qws;

    // zero atomic-accumulation targets; rowmap to -1
    (void)hipMemsetAsync(ws, 0, 3 * 40960 * sizeof(float), stream);
    (void)hipMemsetAsync(out, 0, 40960 * sizeof(float), stream);
    (void)hipMemsetAsync(rowmap, 0xFF, CACHE_N * sizeof(int), stream);

    build_rowmap<<<1, 64, 0, stream>>>(pos, rowmap);

    // 1. q/k/v projections
    gemm_qkv<<<dim3(NSTATE / 64, 4, 3), 256, 0, stream>>>(x, Wq, bq, Wk, Wv, bv, qws, kws, vws);

    // 2. fused cache-update + attention partials
    attn_fused<<<dim3(NSPLIT, H), 256, 0, stream>>>(qws, kci, vci, kws, vws, rowmap, mask,
                                                    kc, vc, mpart, lpart, opart);

    // 3. combine splits
    attn_combine<<<dim3(Q, H), 64, 0, stream>>>(mpart, lpart, opart, oattn);

    // 4. output projection
    gemm_one<<<dim3(NSTATE / 64, 4), 256, 0, stream>>>(oattn, Wout, bout, out);
}